// Round 5
// baseline (43.762 us; speedup 1.0000x reference)
//
#include <hip/hip_runtime.h>

#define LSTREAM 512
#define C 8
#define OUTD 584    // 8 + 64 + 512
#define NW 16       // waves per block (segments per batch)
#define SEG 32      // increments per segment (row 511 zero-padded -> all waves do 32)
#define INCF 4096   // 512 rows x 8 floats
#define PSTRIDE 600 // partial-signature stride in floats

#define RDLANE(v, m) __int_as_float(__builtin_amdgcn_readlane(__float_as_int(v), (m)))

// Chen combine: state (a, in regs) <- a (x) b (in LDS at bp). a is earlier.
// Lane = i*8+j owns a2[i][j] (s2), a3[i][j][0..7] (s3); s1i = a1[i].
__device__ __forceinline__ void chen_combine(const float* bp, int i, int j, int lane,
                                             float& s1i, float& s2, float (&s3)[C]) {
    const float  b1i  = bp[i];
    const float  b1j  = bp[j];
    const float4 b1lo = *reinterpret_cast<const float4*>(bp);
    const float4 b1hi = *reinterpret_cast<const float4*>(bp + 4);
    const float4 b2lo = *reinterpret_cast<const float4*>(bp + C + j * C);
    const float4 b2hi = *reinterpret_cast<const float4*>(bp + C + j * C + 4);
    const float  b2ij = bp[C + lane];
    const float4 b3lo = *reinterpret_cast<const float4*>(bp + C + 64 + lane * C);
    const float4 b3hi = *reinterpret_cast<const float4*>(bp + C + 64 + lane * C + 4);
    const float b1k[C]  = {b1lo.x, b1lo.y, b1lo.z, b1lo.w, b1hi.x, b1hi.y, b1hi.z, b1hi.w};
    const float b2jk[C] = {b2lo.x, b2lo.y, b2lo.z, b2lo.w, b2hi.x, b2hi.y, b2hi.z, b2hi.w};
    const float b3k[C]  = {b3lo.x, b3lo.y, b3lo.z, b3lo.w, b3hi.x, b3hi.y, b3hi.z, b3hi.w};
    #pragma unroll
    for (int k = 0; k < C; ++k)
        s3[k] = s3[k] + b3k[k] + s1i * b2jk[k] + s2 * b1k[k];
    s2 = s2 + b2ij + s1i * b1j;
    s1i += b1i;
}

__device__ __forceinline__ void store_partial(float* pp, int i, int j, int lane,
                                              float s1i, float s2, const float (&s3)[C]) {
    if (j == 0) pp[i] = s1i;
    pp[C + lane] = s2;
    #pragma unroll
    for (int k = 0; k < C; ++k) pp[C + 64 + lane * C + k] = s3[k];
}

__global__ __launch_bounds__(1024, 8) void sig_kernel(const float* __restrict__ path,
                                                      float* __restrict__ out) {
    __shared__ float inc[INCF];            // 16 KB: increment rows 0..510, row 511 = 0
    __shared__ float part[NW * PSTRIDE];   // 37.5 KB: per-wave partial signatures
    const int b    = blockIdx.x;
    const int tid  = threadIdx.x;
    const int w    = tid >> 6;
    const int lane = tid & 63;

    // ---- pre-pass: increments from global (coalesced); zero-pad row 511 ----
    {
        const int row = tid >> 1;
        float4 d = {0.f, 0.f, 0.f, 0.f};
        if (row < LSTREAM - 1) {
            const float4* p4 = reinterpret_cast<const float4*>(path + (size_t)b * (LSTREAM * C));
            const float4 a = p4[tid];       // (row, half)
            const float4 c = p4[tid + 2];   // (row+1, half)
            d.x = c.x - a.x; d.y = c.y - a.y; d.z = c.z - a.z; d.w = c.w - a.w;
        }
        reinterpret_cast<float4*>(inc)[tid] = d;
    }
    __syncthreads();

    const int i = lane >> 3;
    const int j = lane & 7;

    float s1i = 0.f, s2 = 0.f;
    float s3[C];
    #pragma unroll
    for (int k = 0; k < C; ++k) s3[k] = 0.f;

    // wave w consumes inc rows [w*SEG, w*SEG+32) -- row 511 is a zero no-op
    const int r0 = w * SEG;
    const float* pB = inc + r0 * C + (lane & 31);  // distributed: lane holds float (lane&31) of 4-row block
    const float* pI = inc + r0 * C + i;
    const float* pJ = inc + r0 * C + j;

    float blk = pB[0];
    #pragma unroll
    for (int bb = 0; bb < 8; ++bb) {
        const float blk_next = (bb < 7) ? pB[(bb + 1) * 32] : 0.f;  // prefetch next 4-row block
        #pragma unroll
        for (int tt = 0; tt < 4; ++tt) {
            // wave-uniform row -> SGPRs via readlane (VALU pipe, not LDS)
            const float d0 = RDLANE(blk, tt * 8 + 0);
            const float d1 = RDLANE(blk, tt * 8 + 1);
            const float d2 = RDLANE(blk, tt * 8 + 2);
            const float d3 = RDLANE(blk, tt * 8 + 3);
            const float d4 = RDLANE(blk, tt * 8 + 4);
            const float d5 = RDLANE(blk, tt * 8 + 5);
            const float d6 = RDLANE(blk, tt * 8 + 6);
            const float d7 = RDLANE(blk, tt * 8 + 7);
            // per-lane scalars (conflict-free broadcast b32, base + imm offset)
            const float dxi = pI[(bb * 4 + tt) * C];
            const float dxj = pJ[(bb * 4 + tt) * C];

            const float u  = dxi * dxj;
            const float t1 = s1i * dxj;
            const float coeff = fmaf(u, (1.f / 6.f), fmaf(t1, 0.5f, s2));
            s3[0] = fmaf(coeff, d0, s3[0]);
            s3[1] = fmaf(coeff, d1, s3[1]);
            s3[2] = fmaf(coeff, d2, s3[2]);
            s3[3] = fmaf(coeff, d3, s3[3]);
            s3[4] = fmaf(coeff, d4, s3[4]);
            s3[5] = fmaf(coeff, d5, s3[5]);
            s3[6] = fmaf(coeff, d6, s3[6]);
            s3[7] = fmaf(coeff, d7, s3[7]);
            s2 = fmaf(u, 0.5f, s2) + t1;
            s1i += dxi;
        }
        blk = blk_next;
    }

    // ---- publish partials, tree-combine 16 -> 1 ----
    store_partial(part + w * PSTRIDE, i, j, lane, s1i, s2, s3);
    __syncthreads();

    if ((w & 1) == 0) chen_combine(part + (w + 1) * PSTRIDE, i, j, lane, s1i, s2, s3);
    if (w == 2 || w == 6 || w == 10 || w == 14)
        store_partial(part + w * PSTRIDE, i, j, lane, s1i, s2, s3);
    __syncthreads();

    if ((w & 3) == 0) chen_combine(part + (w + 2) * PSTRIDE, i, j, lane, s1i, s2, s3);
    if (w == 4 || w == 12)
        store_partial(part + w * PSTRIDE, i, j, lane, s1i, s2, s3);
    __syncthreads();

    if ((w & 7) == 0) chen_combine(part + (w + 4) * PSTRIDE, i, j, lane, s1i, s2, s3);
    if (w == 8)
        store_partial(part + w * PSTRIDE, i, j, lane, s1i, s2, s3);
    __syncthreads();

    if (w == 0) {
        chen_combine(part + 8 * PSTRIDE, i, j, lane, s1i, s2, s3);
        float* ob = out + (size_t)b * OUTD;
        const float s1out = __shfl(s1i, (lane << 3) & 63, 64);
        if (lane < C) ob[lane] = s1out;
        ob[C + lane] = s2;
        #pragma unroll
        for (int k = 0; k < C; ++k) ob[C + 64 + lane * C + k] = s3[k];
    }
}

extern "C" void kernel_launch(void* const* d_in, const int* in_sizes, int n_in,
                              void* d_out, int out_size, void* d_ws, size_t ws_size,
                              hipStream_t stream) {
    const float* path = (const float*)d_in[0];
    float* out = (float*)d_out;
    const int B = in_sizes[0] / (LSTREAM * C);
    sig_kernel<<<B, 1024, 0, stream>>>(path, out);
}